// Round 10
// baseline (141.058 us; speedup 1.0000x reference)
//
#include <hip/hip_runtime.h>

constexpr int DMODEL = 1024;
constexpr int NHEAD  = 16;
constexpr int DKH    = 64;
constexpr int BATCH  = 2;
constexpr int SEQ    = 2048;
constexpr int MTOT   = BATCH * SEQ;   // 4096
constexpr float SCL  = 0.18033688011112042f;   // (1/sqrt(64)) * log2(e)

typedef __attribute__((ext_vector_type(8))) short short8;
typedef __attribute__((ext_vector_type(4))) float floatx4;

// fp32 -> bf16 round-to-nearest-even
__device__ __forceinline__ ushort f2bf(float f) {
    unsigned u = __builtin_bit_cast(unsigned, f);
    u = (u + 0x7fffu + ((u >> 16) & 1u)) >> 16;
    return (ushort)u;
}

// async 16B global->LDS (HW writes lds_base + lane*16)
__device__ __forceinline__ void gld16(const ushort* g, ushort* l) {
    __builtin_amdgcn_global_load_lds(
        (const __attribute__((address_space(1))) void*)g,
        (__attribute__((address_space(3))) void*)l, 16, 0, 0);
}

// ---------------------------------------------------------------------------
// Convert pass: x -> xb bf16; Wq/Wk/Wv -> wc bf16 [3072,1024]; Wo -> wob bf16.
// ---------------------------------------------------------------------------
__global__ __launch_bounds__(256) void cvt_kernel(
    const float* __restrict__ x,  const float* __restrict__ wq,
    const float* __restrict__ wk, const float* __restrict__ wv,
    const float* __restrict__ wo,
    ushort* __restrict__ xb, ushort* __restrict__ wc, ushort* __restrict__ wob) {
    const int id = blockIdx.x * 256 + threadIdx.x;        // 0 .. 2M-1
    const float* src;
    ushort* dst;
    if (id < (1 << 20)) {
        src = x + (size_t)id * 4;
        dst = xb + (size_t)id * 4;
    } else {
        const int t = id - (1 << 20);
        const int seg = t >> 18;                           // 0..3
        const size_t off = (size_t)(t & 0x3ffff) * 4;
        src = (seg == 0 ? wq : seg == 1 ? wk : seg == 2 ? wv : wo) + off;
        dst = (seg < 3) ? (wc + ((size_t)seg << 20) + off) : (wob + off);
    }
    const float4 v = *(const float4*)src;
    uint2 o;
    o.x = (uint)f2bf(v.x) | ((uint)f2bf(v.y) << 16);
    o.y = (uint)f2bf(v.z) | ((uint)f2bf(v.w) << 16);
    *(uint2*)dst = o;
}

// ---------------------------------------------------------------------------
// bf16 GEMM  Y = A @ W^T + bias (NT).  BK=64, global_load_lds(16B), XOR
// swizzle via pre-swizzled global source.  1D grid + XCD-chunked remap (T1):
// each XCD gets a contiguous nid chunk -> B-panel reuse stays in one L2.
// NMT = number of M-tiles (power of two).
// MODE 0: fused QKV epilogue -> Q^T [B,H,64,S] (scaled), K [B,H,S,64],
//         V^T [B,H,64,S].   MODE 1: fp32 [M,1024] output.
// ---------------------------------------------------------------------------
template <int BMT, int MODE, int NMT, int LOGN>
__global__ __launch_bounds__(256) void gemm_bf16(
    const ushort* __restrict__ A, const ushort* __restrict__ W,
    const float* __restrict__ bias0, const float* __restrict__ bias1,
    const float* __restrict__ bias2,
    ushort* __restrict__ Oq, ushort* __restrict__ Ok, ushort* __restrict__ Ov,
    float* __restrict__ Of) {
    constexpr int BM = 64 * BMT, BN = 128, BK = 64;
    constexpr int MI = 2 * BMT;
    constexpr int CA = BM / 8, CT = CA + BN / 8, NISS = CT / 4;
    __shared__ ushort Als[BM * BK];
    __shared__ ushort Bls[BN * BK];

    const int tid = threadIdx.x;
    const int w = tid >> 6, l = tid & 63;
    const int lr = l & 15, lg = l >> 4;
    const int wm = w >> 1, wn = w & 1;
    // T1 XCD-chunked remap (gridDim.x divisible by 8)
    const int cpx = gridDim.x >> 3;
    const int nid = (blockIdx.x & 7) * cpx + (blockIdx.x >> 3);
    const int m0 = (nid & (NMT - 1)) * BM, n0 = (nid >> LOGN) * BN;

    floatx4 acc[MI][4] = {};

    for (int k0 = 0; k0 < DMODEL; k0 += BK) {
        __syncthreads();
#pragma unroll
        for (int i = 0; i < NISS; i++) {
            const int c = w * NISS + i;
            const int cc = (c < CA) ? c : c - CA;
            const int row = (cc << 3) + (l >> 3);
            const int gcol = (((l & 7) ^ (row & 7)) << 3);
            if (c < CA)
                gld16(A + (size_t)(m0 + row) * DMODEL + k0 + gcol, &Als[cc << 9]);
            else
                gld16(W + (size_t)(n0 + row) * DMODEL + k0 + gcol, &Bls[cc << 9]);
        }
        __syncthreads();

#pragma unroll
        for (int kk = 0; kk < 2; kk++) {
            short8 af[MI], bfv[4];
            const int u = kk * 4 + lg;
#pragma unroll
            for (int i = 0; i < MI; i++) {
                const int r = wm * (BM / 2) + i * 16 + lr;
                af[i] = *(const short8*)&Als[r * 64 + ((u ^ (r & 7)) << 3)];
            }
#pragma unroll
            for (int j = 0; j < 4; j++) {
                const int r = wn * 64 + j * 16 + lr;
                bfv[j] = *(const short8*)&Bls[r * 64 + ((u ^ (r & 7)) << 3)];
            }
#pragma unroll
            for (int i = 0; i < MI; i++)
#pragma unroll
                for (int j = 0; j < 4; j++)
                    acc[i][j] = __builtin_amdgcn_mfma_f32_16x16x32_bf16(af[i], bfv[j], acc[i][j], 0, 0, 0);
        }
    }

#pragma unroll
    for (int i = 0; i < MI; i++) {
        const int rbase = m0 + wm * (BM / 2) + i * 16 + lg * 4;
#pragma unroll
        for (int j = 0; j < 4; j++) {
            const int cg = n0 + wn * 64 + j * 16 + lr;
            if constexpr (MODE == 1) {
                const float bb = bias0[cg];
#pragma unroll
                for (int p = 0; p < 4; p++)
                    Of[(size_t)(rbase + p) * DMODEL + cg] = acc[i][j][p] + bb;
            } else {
                const int sel = cg >> 10, cw = cg & 1023;
                const int h = cw >> 6, d = cw & 63;
                const float bb = (sel == 0 ? bias0 : sel == 1 ? bias1 : bias2)[cw];
                const int b = rbase >> 11, s = rbase & (SEQ - 1);
                if (sel == 2) {
                    uint2 pk;
                    pk.x = (uint)f2bf(acc[i][j][0] + bb) | ((uint)f2bf(acc[i][j][1] + bb) << 16);
                    pk.y = (uint)f2bf(acc[i][j][2] + bb) | ((uint)f2bf(acc[i][j][3] + bb) << 16);
                    *(uint2*)&Ov[((size_t)(b * NHEAD + h) * DKH + d) * SEQ + s] = pk;
                } else if (sel == 0) {
                    // Q transposed [B,H,64,S], pre-scaled: packed like V
                    uint2 pk;
                    pk.x = (uint)f2bf((acc[i][j][0] + bb) * SCL) |
                           ((uint)f2bf((acc[i][j][1] + bb) * SCL) << 16);
                    pk.y = (uint)f2bf((acc[i][j][2] + bb) * SCL) |
                           ((uint)f2bf((acc[i][j][3] + bb) * SCL) << 16);
                    *(uint2*)&Oq[((size_t)(b * NHEAD + h) * DKH + d) * SEQ + s] = pk;
                } else {
#pragma unroll
                    for (int p = 0; p < 4; p++)
                        Ok[((size_t)(b * NHEAD + h) * SEQ + s + p) * DKH + d] = f2bf(acc[i][j][p] + bb);
                }
            }
        }
    }
}

// ---------------------------------------------------------------------------
// Flash attention, swapped QK^T in-lane softmax + T3-minimum double-buffer
// + T5 setprio + T12 cvt_pk + T13 defer-max + l-sum via ones-column MFMA.
// T1 XCD remap: all 16 q-tiles of a head land on ONE XCD so its K/V (512KB)
// stays L2-resident -> prefetch covers L2 latency, not HBM.
//   linear id l = (bh%8) + 8*qt + 128*(bh/8)  (bijective on [0,512))
// Q input TRANSPOSED [B,H,64,S] (pre-scaled).  1D grid 512, 512 thr = 8 waves.
// ---------------------------------------------------------------------------
__global__ __launch_bounds__(512) void attn_kernel(
    const ushort* __restrict__ Qt, const ushort* __restrict__ K,
    const ushort* __restrict__ Vt, ushort* __restrict__ O) {
    constexpr int KT = 64, NT = SEQ / KT;
    __shared__ ushort Kls0[KT * 64], Kls1[KT * 64];   // [kpos][d], swizzled slots
    __shared__ ushort Vls0[KT * 64], Vls1[KT * 64];   // [d][kpos], swizzled slots
    __shared__ ushort Pls[8][16][68];                 // per-wave P [q][k]

    const int tid = threadIdx.x;
    const int w = tid >> 6, l = tid & 63;
    const int lr = l & 15, lg = l >> 4;
    const int lg4 = lg * 4;
    // T1 remap: same-head blocks share an XCD
    const int l0 = blockIdx.x;
    const int bh = (l0 & 7) + ((l0 >> 7) << 3);
    const int q0 = ((l0 >> 3) & 15) * 128;
    const ushort* Qh = Qt + (size_t)bh * DKH * SEQ;
    const ushort* Kh = K  + (size_t)bh * SEQ * DKH;
    const ushort* Vh = Vt + (size_t)bh * DKH * SEQ;

    // Q fragments (B-operand of swapped QK^T) from transposed Q: col = q = lr
    short8 qf[2];
#pragma unroll
    for (int kk = 0; kk < 2; kk++)
#pragma unroll
        for (int j = 0; j < 8; j++)
            ((ushort*)&qf[kk])[j] =
                Qh[(size_t)(kk * 32 + lg * 8 + j) * SEQ + q0 + w * 16 + lr];

    // bf16 ones vector for the l-sum MFMA column
    short8 ones;
#pragma unroll
    for (int j = 0; j < 8; j++) ones[j] = (short)0x3F80;

    // staging: wave w stages rows w*8..w*8+7; per-lane global col pre-swizzled
    const int srow = w * 8 + (l >> 3);
    const int scol = ((l & 7) ^ ((l >> 3) & 7)) * 8;
    const ushort* Kg = Kh + (size_t)srow * DKH + scol;
    const ushort* Vg = Vh + (size_t)srow * SEQ + scol;

    floatx4 acc[4] = {};
    floatx4 accl = {};
    float mrun = -3e38f;

// t = TILE index: K tile t starts at row t*KT; V^T tile t at column t*KT.
#define STAGE(t, kdst, vdst)                                          \
    do {                                                              \
        gld16(Kg + (size_t)(t) * (KT * DKH), (kdst) + w * 512);       \
        gld16(Vg + (size_t)(t) * KT, (vdst) + w * 512);               \
    } while (0)

#define COMPUTE(kb, vb)                                                         \
    do {                                                                        \
        floatx4 sa[4] = {};                                                     \
        __builtin_amdgcn_s_setprio(1);                                          \
        _Pragma("unroll")                                                       \
        for (int kk = 0; kk < 2; kk++) {                                        \
            const int u = kk * 4 + lg;                                          \
            _Pragma("unroll")                                                   \
            for (int n = 0; n < 4; n++) {                                       \
                const int r = n * 16 + lr;                                      \
                const short8 kf = *(const short8*)&(kb)[r * 64 + ((u ^ (r & 7)) << 3)]; \
                sa[n] = __builtin_amdgcn_mfma_f32_16x16x32_bf16(kf, qf[kk], sa[n], 0, 0, 0); \
            }                                                                   \
        }                                                                       \
        __builtin_amdgcn_s_setprio(0);                                          \
        float mx = fmaxf(fmaxf(fmaxf(sa[0][0], sa[0][1]), fmaxf(sa[0][2], sa[0][3])), \
                         fmaxf(fmaxf(sa[1][0], sa[1][1]), fmaxf(sa[1][2], sa[1][3]))); \
        mx = fmaxf(mx, fmaxf(fmaxf(fmaxf(sa[2][0], sa[2][1]), fmaxf(sa[2][2], sa[2][3])), \
                             fmaxf(fmaxf(sa[3][0], sa[3][1]), fmaxf(sa[3][2], sa[3][3])))); \
        mx = fmaxf(mx, __shfl_xor(mx, 16));                                     \
        mx = fmaxf(mx, __shfl_xor(mx, 32));                                     \
        if (__any(mx - mrun > 10.0f)) {   /* T13 defer-max */                   \
            const float mn = fmaxf(mrun, mx);                                   \
            const float corr = exp2f(mrun - mn);                                \
            mrun = mn;                                                          \
            _Pragma("unroll")                                                   \
            for (int p = 0; p < 4; p++) {                                       \
                const float cp = __shfl(corr, lg4 + p);                         \
                _Pragma("unroll")                                               \
                for (int n = 0; n < 4; n++) acc[n][p] *= cp;                    \
                accl[p] *= cp;                                                  \
            }                                                                   \
        }                                                                       \
        _Pragma("unroll")                                                       \
        for (int n = 0; n < 4; n++)                                             \
            _Pragma("unroll")                                                   \
            for (int p = 0; p < 4; p++)                                         \
                sa[n][p] = exp2f(sa[n][p] - mrun);                              \
        _Pragma("unroll")                                                       \
        for (int n = 0; n < 4; n++) {   /* T12 cvt_pk */                        \
            uint2 pk;                                                           \
            asm("v_cvt_pk_bf16_f32 %0, %1, %2" : "=v"(pk.x) : "v"(sa[n][0]), "v"(sa[n][1])); \
            asm("v_cvt_pk_bf16_f32 %0, %1, %2" : "=v"(pk.y) : "v"(sa[n][2]), "v"(sa[n][3])); \
            *(uint2*)&Pls[w][lr][n * 16 + lg4] = pk;                            \
        }                                                                       \
        __builtin_amdgcn_s_setprio(1);                                          \
        _Pragma("unroll")                                                       \
        for (int kk = 0; kk < 2; kk++) {                                        \
            const int u = kk * 4 + lg;                                          \
            const short8 pf = *(const short8*)&Pls[w][lr][kk * 32 + lg * 8];    \
            _Pragma("unroll")                                                   \
            for (int n = 0; n < 4; n++) {                                       \
                const int r = n * 16 + lr;                                      \
                const short8 vf = *(const short8*)&(vb)[r * 64 + ((u ^ (r & 7)) << 3)]; \
                acc[n] = __builtin_amdgcn_mfma_f32_16x16x32_bf16(pf, vf, acc[n], 0, 0, 0); \
            }                                                                   \
            accl = __builtin_amdgcn_mfma_f32_16x16x32_bf16(pf, ones, accl, 0, 0, 0); \
        }                                                                       \
        __builtin_amdgcn_s_setprio(0);                                          \
    } while (0)

    // T3-minimum pipeline: prefetch next tile before computing current;
    // one barrier per tile (drains vmcnt -> prefetched tile ready).
    STAGE(0, Kls0, Vls0);
    __syncthreads();
#pragma unroll 1
    for (int it = 0; it < NT / 2 - 1; it++) {
        STAGE(2 * it + 1, Kls1, Vls1);
        COMPUTE(Kls0, Vls0);
        __syncthreads();
        STAGE(2 * it + 2, Kls0, Vls0);
        COMPUTE(Kls1, Vls1);
        __syncthreads();
    }
    STAGE(NT - 1, Kls1, Vls1);
    COMPUTE(Kls0, Vls0);
    __syncthreads();
    COMPUTE(Kls1, Vls1);
#undef STAGE
#undef COMPUTE

    // epilogue: O row = q = w*16 + lg4+p (same indexing as accl), col = h*64+n*16+lr
    const int b = bh >> 4, h = bh & (NHEAD - 1);
#pragma unroll
    for (int p = 0; p < 4; p++) {
        const float inv = 1.0f / accl[p];
        const int sr = q0 + w * 16 + lg4 + p;
#pragma unroll
        for (int n = 0; n < 4; n++) {
            const int d = n * 16 + lr;
            O[((size_t)(b * SEQ + sr)) * DMODEL + h * DKH + d] = f2bf(acc[n][p] * inv);
        }
    }
}

// ---------------------------------------------------------------------------
extern "C" void kernel_launch(void* const* d_in, const int* in_sizes, int n_in,
                              void* d_out, int out_size, void* d_ws, size_t ws_size,
                              hipStream_t stream) {
    const float* x  = (const float*)d_in[0];
    const float* Wq = (const float*)d_in[1];
    const float* bq = (const float*)d_in[2];
    const float* Wk = (const float*)d_in[3];
    const float* bk = (const float*)d_in[4];
    const float* Wv = (const float*)d_in[5];
    const float* bv = (const float*)d_in[6];
    const float* Wo = (const float*)d_in[7];
    const float* bo = (const float*)d_in[8];

    ushort* base = (ushort*)d_ws;
    ushort* xb  = base;                                  // 4M bf16
    ushort* wc  = xb  + (size_t)4 * 1024 * 1024;         // 3M  (Wq|Wk|Wv)
    ushort* wob = wc  + (size_t)3 * 1024 * 1024;         // 1M
    ushort* qws = wob + (size_t)1 * 1024 * 1024;         // 4M  Q^T [B,H,64,S] (pre-scaled)
    ushort* kws = qws + (size_t)4 * 1024 * 1024;         // 4M  K [B,H,S,64]
    ushort* vws = kws + (size_t)4 * 1024 * 1024;         // 4M  V^T [B,H,64,S]
    ushort* aws = vws + (size_t)4 * 1024 * 1024;         // 4M  attn out bf16

    hipLaunchKernelGGL(cvt_kernel, dim3(8192), dim3(256), 0, stream,
                       x, Wq, Wk, Wv, Wo, xb, wc, wob);

    // QKV: 32 M-tiles x 24 N-tiles = 768 blocks (1D, XCD-chunked in-kernel)
    hipLaunchKernelGGL((gemm_bf16<2, 0, 32, 5>), dim3(768), dim3(256), 0, stream,
                       xb, wc, bq, bk, bv, qws, kws, vws, (float*)nullptr);

    hipLaunchKernelGGL(attn_kernel, dim3(512), dim3(512), 0, stream,
                       qws, kws, vws, aws);

    // out-proj: 64 M-tiles x 8 N-tiles = 512 blocks
    hipLaunchKernelGGL((gemm_bf16<1, 1, 64, 6>), dim3(512), dim3(256), 0, stream,
                       aws, wob, bo, (const float*)nullptr, (const float*)nullptr,
                       (ushort*)nullptr, (ushort*)nullptr, (ushort*)nullptr, (float*)d_out);
}

// Round 11
// 140.759 us; speedup vs baseline: 1.0021x; 1.0021x over previous
//
#include <hip/hip_runtime.h>

constexpr int DMODEL = 1024;
constexpr int NHEAD  = 16;
constexpr int DKH    = 64;
constexpr int BATCH  = 2;
constexpr int SEQ    = 2048;
constexpr int MTOT   = BATCH * SEQ;   // 4096
constexpr float SCL  = 0.18033688011112042f;   // (1/sqrt(64)) * log2(e)

typedef __attribute__((ext_vector_type(8))) short short8;
typedef __attribute__((ext_vector_type(4))) float floatx4;

// fp32 -> bf16 round-to-nearest-even
__device__ __forceinline__ ushort f2bf(float f) {
    unsigned u = __builtin_bit_cast(unsigned, f);
    u = (u + 0x7fffu + ((u >> 16) & 1u)) >> 16;
    return (ushort)u;
}

// async 16B global->LDS (HW writes lds_base + lane*16)
__device__ __forceinline__ void gld16(const ushort* g, ushort* l) {
    __builtin_amdgcn_global_load_lds(
        (const __attribute__((address_space(1))) void*)g,
        (__attribute__((address_space(3))) void*)l, 16, 0, 0);
}

// ---------------------------------------------------------------------------
// Convert pass: x -> xb bf16; Wq/Wk/Wv -> wc bf16 [3072,1024]; Wo -> wob bf16.
// ---------------------------------------------------------------------------
__global__ __launch_bounds__(256) void cvt_kernel(
    const float* __restrict__ x,  const float* __restrict__ wq,
    const float* __restrict__ wk, const float* __restrict__ wv,
    const float* __restrict__ wo,
    ushort* __restrict__ xb, ushort* __restrict__ wc, ushort* __restrict__ wob) {
    const int id = blockIdx.x * 256 + threadIdx.x;        // 0 .. 2M-1
    const float* src;
    ushort* dst;
    if (id < (1 << 20)) {
        src = x + (size_t)id * 4;
        dst = xb + (size_t)id * 4;
    } else {
        const int t = id - (1 << 20);
        const int seg = t >> 18;                           // 0..3
        const size_t off = (size_t)(t & 0x3ffff) * 4;
        src = (seg == 0 ? wq : seg == 1 ? wk : seg == 2 ? wv : wo) + off;
        dst = (seg < 3) ? (wc + ((size_t)seg << 20) + off) : (wob + off);
    }
    const float4 v = *(const float4*)src;
    uint2 o;
    o.x = (uint)f2bf(v.x) | ((uint)f2bf(v.y) << 16);
    o.y = (uint)f2bf(v.z) | ((uint)f2bf(v.w) << 16);
    *(uint2*)dst = o;
}

// ---------------------------------------------------------------------------
// bf16 GEMM  Y = A @ W^T + bias (NT).  BK=64, global_load_lds(16B), XOR
// swizzle via pre-swizzled global source.  2D grid (r9 form — the 1D XCD
// remap regressed 5.7us in r10 and was reverted).
// MODE 0: fused QKV epilogue -> Q^T [B,H,64,S] (scaled), K [B,H,S,64],
//         V^T [B,H,64,S].   MODE 1: fp32 [M,1024] output.
// ---------------------------------------------------------------------------
template <int BMT, int MODE>
__global__ __launch_bounds__(256) void gemm_bf16(
    const ushort* __restrict__ A, const ushort* __restrict__ W,
    const float* __restrict__ bias0, const float* __restrict__ bias1,
    const float* __restrict__ bias2,
    ushort* __restrict__ Oq, ushort* __restrict__ Ok, ushort* __restrict__ Ov,
    float* __restrict__ Of) {
    constexpr int BM = 64 * BMT, BN = 128, BK = 64;
    constexpr int MI = 2 * BMT;
    constexpr int CA = BM / 8, CT = CA + BN / 8, NISS = CT / 4;
    __shared__ ushort Als[BM * BK];
    __shared__ ushort Bls[BN * BK];

    const int tid = threadIdx.x;
    const int w = tid >> 6, l = tid & 63;
    const int lr = l & 15, lg = l >> 4;
    const int wm = w >> 1, wn = w & 1;
    const int m0 = blockIdx.x * BM, n0 = blockIdx.y * BN;

    floatx4 acc[MI][4] = {};

    for (int k0 = 0; k0 < DMODEL; k0 += BK) {
        __syncthreads();
#pragma unroll
        for (int i = 0; i < NISS; i++) {
            const int c = w * NISS + i;
            const int cc = (c < CA) ? c : c - CA;
            const int row = (cc << 3) + (l >> 3);
            const int gcol = (((l & 7) ^ (row & 7)) << 3);
            if (c < CA)
                gld16(A + (size_t)(m0 + row) * DMODEL + k0 + gcol, &Als[cc << 9]);
            else
                gld16(W + (size_t)(n0 + row) * DMODEL + k0 + gcol, &Bls[cc << 9]);
        }
        __syncthreads();

#pragma unroll
        for (int kk = 0; kk < 2; kk++) {
            short8 af[MI], bfv[4];
            const int u = kk * 4 + lg;
#pragma unroll
            for (int i = 0; i < MI; i++) {
                const int r = wm * (BM / 2) + i * 16 + lr;
                af[i] = *(const short8*)&Als[r * 64 + ((u ^ (r & 7)) << 3)];
            }
#pragma unroll
            for (int j = 0; j < 4; j++) {
                const int r = wn * 64 + j * 16 + lr;
                bfv[j] = *(const short8*)&Bls[r * 64 + ((u ^ (r & 7)) << 3)];
            }
#pragma unroll
            for (int i = 0; i < MI; i++)
#pragma unroll
                for (int j = 0; j < 4; j++)
                    acc[i][j] = __builtin_amdgcn_mfma_f32_16x16x32_bf16(af[i], bfv[j], acc[i][j], 0, 0, 0);
        }
    }

#pragma unroll
    for (int i = 0; i < MI; i++) {
        const int rbase = m0 + wm * (BM / 2) + i * 16 + lg * 4;
#pragma unroll
        for (int j = 0; j < 4; j++) {
            const int cg = n0 + wn * 64 + j * 16 + lr;
            if constexpr (MODE == 1) {
                const float bb = bias0[cg];
#pragma unroll
                for (int p = 0; p < 4; p++)
                    Of[(size_t)(rbase + p) * DMODEL + cg] = acc[i][j][p] + bb;
            } else {
                const int sel = cg >> 10, cw = cg & 1023;
                const int h = cw >> 6, d = cw & 63;
                const float bb = (sel == 0 ? bias0 : sel == 1 ? bias1 : bias2)[cw];
                const int b = rbase >> 11, s = rbase & (SEQ - 1);
                if (sel == 2) {
                    uint2 pk;
                    pk.x = (uint)f2bf(acc[i][j][0] + bb) | ((uint)f2bf(acc[i][j][1] + bb) << 16);
                    pk.y = (uint)f2bf(acc[i][j][2] + bb) | ((uint)f2bf(acc[i][j][3] + bb) << 16);
                    *(uint2*)&Ov[((size_t)(b * NHEAD + h) * DKH + d) * SEQ + s] = pk;
                } else if (sel == 0) {
                    // Q transposed [B,H,64,S], pre-scaled: packed like V
                    uint2 pk;
                    pk.x = (uint)f2bf((acc[i][j][0] + bb) * SCL) |
                           ((uint)f2bf((acc[i][j][1] + bb) * SCL) << 16);
                    pk.y = (uint)f2bf((acc[i][j][2] + bb) * SCL) |
                           ((uint)f2bf((acc[i][j][3] + bb) * SCL) << 16);
                    *(uint2*)&Oq[((size_t)(b * NHEAD + h) * DKH + d) * SEQ + s] = pk;
                } else {
#pragma unroll
                    for (int p = 0; p < 4; p++)
                        Ok[((size_t)(b * NHEAD + h) * SEQ + s + p) * DKH + d] = f2bf(acc[i][j][p] + bb);
                }
            }
        }
    }
}

// ---------------------------------------------------------------------------
// Flash attention.  QT=256: 8 waves x 32 q-rows each -> every kf/vf LDS
// fragment is read ONCE and feeds BOTH 16-q halves (2x MFMA per LDS read,
// -45% LDS traffic vs QT=128).  Swapped QK^T in-lane softmax + T3 dbuf +
// T5 setprio + T12 cvt_pk + T13 defer-max + l-sum ones-MFMA + T1 XCD remap
// (all 8 q-tiles of a head on one XCD; 4 heads x 512KB = 2MB per L2).
// Grid 256 blocks x 512 threads.  Q input TRANSPOSED [B,H,64,S] (pre-scaled).
// ---------------------------------------------------------------------------
__global__ __launch_bounds__(512) void attn_kernel(
    const ushort* __restrict__ Qt, const ushort* __restrict__ K,
    const ushort* __restrict__ Vt, ushort* __restrict__ O) {
    constexpr int KT = 64, NT = SEQ / KT;
    __shared__ ushort Kls0[KT * 64], Kls1[KT * 64];   // [kpos][d], swizzled slots
    __shared__ ushort Vls0[KT * 64], Vls1[KT * 64];   // [d][kpos], swizzled slots
    __shared__ ushort Pls[8][32][68];                 // per-wave P [q][k]

    const int tid = threadIdx.x;
    const int w = tid >> 6, l = tid & 63;
    const int lr = l & 15, lg = l >> 4;
    const int lg4 = lg * 4;
    // T1 remap (256 blocks): bh = (l0&7) + 8*(l0>>6), qt = (l0>>3)&7
    const int l0 = blockIdx.x;
    const int bh = (l0 & 7) + ((l0 >> 6) << 3);
    const int q0 = ((l0 >> 3) & 7) * 256;
    const int qb = q0 + w * 32;                       // wave's 32-q base
    const ushort* Qh = Qt + (size_t)bh * DKH * SEQ;
    const ushort* Kh = K  + (size_t)bh * SEQ * DKH;
    const ushort* Vh = Vt + (size_t)bh * DKH * SEQ;

    // Q fragments: halves hh=0,1 cover q = qb+hh*16+lr
    short8 qf[2][2];
#pragma unroll
    for (int hh = 0; hh < 2; hh++)
#pragma unroll
        for (int kk = 0; kk < 2; kk++)
#pragma unroll
            for (int j = 0; j < 8; j++)
                ((ushort*)&qf[hh][kk])[j] =
                    Qh[(size_t)(kk * 32 + lg * 8 + j) * SEQ + qb + hh * 16 + lr];

    // bf16 ones vector for the l-sum MFMA column
    short8 ones;
#pragma unroll
    for (int j = 0; j < 8; j++) ones[j] = (short)0x3F80;

    // staging: wave w stages rows w*8..w*8+7; per-lane global col pre-swizzled
    const int srow = w * 8 + (l >> 3);
    const int scol = ((l & 7) ^ ((l >> 3) & 7)) * 8;
    const ushort* Kg = Kh + (size_t)srow * DKH + scol;
    const ushort* Vg = Vh + (size_t)srow * SEQ + scol;

    floatx4 acc[2][4] = {};
    floatx4 accl[2] = {};
    float mrun[2] = {-3e38f, -3e38f};

// t = TILE index: K tile t starts at row t*KT; V^T tile t at column t*KT.
#define STAGE(t, kdst, vdst)                                          \
    do {                                                              \
        gld16(Kg + (size_t)(t) * (KT * DKH), (kdst) + w * 512);       \
        gld16(Vg + (size_t)(t) * KT, (vdst) + w * 512);               \
    } while (0)

#define COMPUTE(kb, vb)                                                         \
    do {                                                                        \
        floatx4 sa[2][4] = {};                                                  \
        __builtin_amdgcn_s_setprio(1);                                          \
        _Pragma("unroll")                                                       \
        for (int kk = 0; kk < 2; kk++) {                                        \
            const int u = kk * 4 + lg;                                          \
            _Pragma("unroll")                                                   \
            for (int n = 0; n < 4; n++) {                                       \
                const int r = n * 16 + lr;                                      \
                const short8 kf = *(const short8*)&(kb)[r * 64 + ((u ^ (r & 7)) << 3)]; \
                sa[0][n] = __builtin_amdgcn_mfma_f32_16x16x32_bf16(kf, qf[0][kk], sa[0][n], 0, 0, 0); \
                sa[1][n] = __builtin_amdgcn_mfma_f32_16x16x32_bf16(kf, qf[1][kk], sa[1][n], 0, 0, 0); \
            }                                                                   \
        }                                                                       \
        __builtin_amdgcn_s_setprio(0);                                          \
        _Pragma("unroll")                                                       \
        for (int hh = 0; hh < 2; hh++) {                                        \
            float mx = fmaxf(fmaxf(fmaxf(sa[hh][0][0], sa[hh][0][1]), fmaxf(sa[hh][0][2], sa[hh][0][3])), \
                             fmaxf(fmaxf(sa[hh][1][0], sa[hh][1][1]), fmaxf(sa[hh][1][2], sa[hh][1][3]))); \
            mx = fmaxf(mx, fmaxf(fmaxf(fmaxf(sa[hh][2][0], sa[hh][2][1]), fmaxf(sa[hh][2][2], sa[hh][2][3])), \
                                 fmaxf(fmaxf(sa[hh][3][0], sa[hh][3][1]), fmaxf(sa[hh][3][2], sa[hh][3][3])))); \
            mx = fmaxf(mx, __shfl_xor(mx, 16));                                 \
            mx = fmaxf(mx, __shfl_xor(mx, 32));                                 \
            if (__any(mx - mrun[hh] > 10.0f)) {   /* T13 defer-max */           \
                const float mn = fmaxf(mrun[hh], mx);                           \
                const float corr = exp2f(mrun[hh] - mn);                        \
                mrun[hh] = mn;                                                  \
                _Pragma("unroll")                                               \
                for (int p = 0; p < 4; p++) {                                   \
                    const float cp = __shfl(corr, lg4 + p);                     \
                    _Pragma("unroll")                                           \
                    for (int n = 0; n < 4; n++) acc[hh][n][p] *= cp;            \
                    accl[hh][p] *= cp;                                          \
                }                                                               \
            }                                                                   \
            _Pragma("unroll")                                                   \
            for (int n = 0; n < 4; n++)                                         \
                _Pragma("unroll")                                               \
                for (int p = 0; p < 4; p++)                                     \
                    sa[hh][n][p] = exp2f(sa[hh][n][p] - mrun[hh]);              \
            _Pragma("unroll")                                                   \
            for (int n = 0; n < 4; n++) {   /* T12 cvt_pk */                    \
                uint2 pk;                                                       \
                asm("v_cvt_pk_bf16_f32 %0, %1, %2" : "=v"(pk.x) : "v"(sa[hh][n][0]), "v"(sa[hh][n][1])); \
                asm("v_cvt_pk_bf16_f32 %0, %1, %2" : "=v"(pk.y) : "v"(sa[hh][n][2]), "v"(sa[hh][n][3])); \
                *(uint2*)&Pls[w][hh * 16 + lr][n * 16 + lg4] = pk;              \
            }                                                                   \
        }                                                                       \
        __builtin_amdgcn_s_setprio(1);                                          \
        _Pragma("unroll")                                                       \
        for (int kk = 0; kk < 2; kk++) {                                        \
            const int u = kk * 4 + lg;                                          \
            const short8 pf0 = *(const short8*)&Pls[w][lr][kk * 32 + lg * 8];   \
            const short8 pf1 = *(const short8*)&Pls[w][16 + lr][kk * 32 + lg * 8]; \
            _Pragma("unroll")                                                   \
            for (int n = 0; n < 4; n++) {                                       \
                const int r = n * 16 + lr;                                      \
                const short8 vf = *(const short8*)&(vb)[r * 64 + ((u ^ (r & 7)) << 3)]; \
                acc[0][n] = __builtin_amdgcn_mfma_f32_16x16x32_bf16(pf0, vf, acc[0][n], 0, 0, 0); \
                acc[1][n] = __builtin_amdgcn_mfma_f32_16x16x32_bf16(pf1, vf, acc[1][n], 0, 0, 0); \
            }                                                                   \
            accl[0] = __builtin_amdgcn_mfma_f32_16x16x32_bf16(pf0, ones, accl[0], 0, 0, 0); \
            accl[1] = __builtin_amdgcn_mfma_f32_16x16x32_bf16(pf1, ones, accl[1], 0, 0, 0); \
        }                                                                       \
        __builtin_amdgcn_s_setprio(0);                                          \
    } while (0)

    // T3-minimum pipeline: prefetch next tile before computing current;
    // one barrier per tile (drains vmcnt -> prefetched tile ready).
    STAGE(0, Kls0, Vls0);
    __syncthreads();
#pragma unroll 1
    for (int it = 0; it < NT / 2 - 1; it++) {
        STAGE(2 * it + 1, Kls1, Vls1);
        COMPUTE(Kls0, Vls0);
        __syncthreads();
        STAGE(2 * it + 2, Kls0, Vls0);
        COMPUTE(Kls1, Vls1);
        __syncthreads();
    }
    STAGE(NT - 1, Kls1, Vls1);
    COMPUTE(Kls0, Vls0);
    __syncthreads();
    COMPUTE(Kls1, Vls1);
#undef STAGE
#undef COMPUTE

    // epilogue: O row q = qb + hh*16 + lg4+p, col = h*64 + n*16+lr
    const int b = bh >> 4, h = bh & (NHEAD - 1);
#pragma unroll
    for (int hh = 0; hh < 2; hh++)
#pragma unroll
        for (int p = 0; p < 4; p++) {
            const float inv = 1.0f / accl[hh][p];
            const int sr = qb + hh * 16 + lg4 + p;
#pragma unroll
            for (int n = 0; n < 4; n++) {
                const int d = n * 16 + lr;
                O[((size_t)(b * SEQ + sr)) * DMODEL + h * DKH + d] = f2bf(acc[hh][n][p] * inv);
            }
        }
}

// ---------------------------------------------------------------------------
extern "C" void kernel_launch(void* const* d_in, const int* in_sizes, int n_in,
                              void* d_out, int out_size, void* d_ws, size_t ws_size,
                              hipStream_t stream) {
    const float* x  = (const float*)d_in[0];
    const float* Wq = (const float*)d_in[1];
    const float* bq = (const float*)d_in[2];
    const float* Wk = (const float*)d_in[3];
    const float* bk = (const float*)d_in[4];
    const float* Wv = (const float*)d_in[5];
    const float* bv = (const float*)d_in[6];
    const float* Wo = (const float*)d_in[7];
    const float* bo = (const float*)d_in[8];

    ushort* base = (ushort*)d_ws;
    ushort* xb  = base;                                  // 4M bf16
    ushort* wc  = xb  + (size_t)4 * 1024 * 1024;         // 3M  (Wq|Wk|Wv)
    ushort* wob = wc  + (size_t)3 * 1024 * 1024;         // 1M
    ushort* qws = wob + (size_t)1 * 1024 * 1024;         // 4M  Q^T [B,H,64,S] (pre-scaled)
    ushort* kws = qws + (size_t)4 * 1024 * 1024;         // 4M  K [B,H,S,64]
    ushort* vws = kws + (size_t)4 * 1024 * 1024;         // 4M  V^T [B,H,64,S]
    ushort* aws = vws + (size_t)4 * 1024 * 1024;         // 4M  attn out bf16

    hipLaunchKernelGGL(cvt_kernel, dim3(8192), dim3(256), 0, stream,
                       x, Wq, Wk, Wv, Wo, xb, wc, wob);

    hipLaunchKernelGGL((gemm_bf16<2, 0>), dim3(MTOT / 128, 3072 / 128), dim3(256), 0, stream,
                       xb, wc, bq, bk, bv, qws, kws, vws, (float*)nullptr);

    hipLaunchKernelGGL(attn_kernel, dim3(256), dim3(512), 0, stream,
                       qws, kws, vws, aws);

    hipLaunchKernelGGL((gemm_bf16<1, 1>), dim3(MTOT / 64, DMODEL / 128), dim3(256), 0, stream,
                       aws, wob, bo, (const float*)nullptr, (const float*)nullptr,
                       (ushort*)nullptr, (ushort*)nullptr, (ushort*)nullptr, (float*)d_out);
}

// Round 12
// 136.076 us; speedup vs baseline: 1.0366x; 1.0344x over previous
//
#include <hip/hip_runtime.h>

constexpr int DMODEL = 1024;
constexpr int NHEAD  = 16;
constexpr int DKH    = 64;
constexpr int BATCH  = 2;
constexpr int SEQ    = 2048;
constexpr int MTOT   = BATCH * SEQ;   // 4096
constexpr float SCL  = 0.18033688011112042f;   // (1/sqrt(64)) * log2(e)

typedef __attribute__((ext_vector_type(8)))  short short8;
typedef __attribute__((ext_vector_type(4)))  float floatx4;
typedef __attribute__((ext_vector_type(16))) float floatx16;
typedef __attribute__((ext_vector_type(4)))  uint  uintx4;

// fp32 -> bf16 round-to-nearest-even
__device__ __forceinline__ ushort f2bf(float f) {
    unsigned u = __builtin_bit_cast(unsigned, f);
    u = (u + 0x7fffu + ((u >> 16) & 1u)) >> 16;
    return (ushort)u;
}

// async 16B global->LDS (HW writes lds_base + lane*16)
__device__ __forceinline__ void gld16(const ushort* g, ushort* l) {
    __builtin_amdgcn_global_load_lds(
        (const __attribute__((address_space(1))) void*)g,
        (__attribute__((address_space(3))) void*)l, 16, 0, 0);
}

// ---------------------------------------------------------------------------
// Convert pass: x -> xb bf16; Wq/Wk/Wv -> wc bf16 [3072,1024]; Wo -> wob bf16.
// ---------------------------------------------------------------------------
__global__ __launch_bounds__(256) void cvt_kernel(
    const float* __restrict__ x,  const float* __restrict__ wq,
    const float* __restrict__ wk, const float* __restrict__ wv,
    const float* __restrict__ wo,
    ushort* __restrict__ xb, ushort* __restrict__ wc, ushort* __restrict__ wob) {
    const int id = blockIdx.x * 256 + threadIdx.x;        // 0 .. 2M-1
    const float* src;
    ushort* dst;
    if (id < (1 << 20)) {
        src = x + (size_t)id * 4;
        dst = xb + (size_t)id * 4;
    } else {
        const int t = id - (1 << 20);
        const int seg = t >> 18;                           // 0..3
        const size_t off = (size_t)(t & 0x3ffff) * 4;
        src = (seg == 0 ? wq : seg == 1 ? wk : seg == 2 ? wv : wo) + off;
        dst = (seg < 3) ? (wc + ((size_t)seg << 20) + off) : (wob + off);
    }
    const float4 v = *(const float4*)src;
    uint2 o;
    o.x = (uint)f2bf(v.x) | ((uint)f2bf(v.y) << 16);
    o.y = (uint)f2bf(v.z) | ((uint)f2bf(v.w) << 16);
    *(uint2*)dst = o;
}

// ---------------------------------------------------------------------------
// bf16 GEMM  Y = A @ W^T + bias (NT).  BK=64, global_load_lds(16B), XOR
// swizzle via pre-swizzled global source.  2D grid (r9 form).
// MODE 0: fused QKV epilogue -> Q^T [B,H,64,S] (scaled), K [B,H,S,64],
//         V^T [B,H,64,S].   MODE 1: fp32 [M,1024] output.
// ---------------------------------------------------------------------------
template <int BMT, int MODE>
__global__ __launch_bounds__(256) void gemm_bf16(
    const ushort* __restrict__ A, const ushort* __restrict__ W,
    const float* __restrict__ bias0, const float* __restrict__ bias1,
    const float* __restrict__ bias2,
    ushort* __restrict__ Oq, ushort* __restrict__ Ok, ushort* __restrict__ Ov,
    float* __restrict__ Of) {
    constexpr int BM = 64 * BMT, BN = 128, BK = 64;
    constexpr int MI = 2 * BMT;
    constexpr int CA = BM / 8, CT = CA + BN / 8, NISS = CT / 4;
    __shared__ ushort Als[BM * BK];
    __shared__ ushort Bls[BN * BK];

    const int tid = threadIdx.x;
    const int w = tid >> 6, l = tid & 63;
    const int lr = l & 15, lg = l >> 4;
    const int wm = w >> 1, wn = w & 1;
    const int m0 = blockIdx.x * BM, n0 = blockIdx.y * BN;

    floatx4 acc[MI][4] = {};

    for (int k0 = 0; k0 < DMODEL; k0 += BK) {
        __syncthreads();
#pragma unroll
        for (int i = 0; i < NISS; i++) {
            const int c = w * NISS + i;
            const int cc = (c < CA) ? c : c - CA;
            const int row = (cc << 3) + (l >> 3);
            const int gcol = (((l & 7) ^ (row & 7)) << 3);
            if (c < CA)
                gld16(A + (size_t)(m0 + row) * DMODEL + k0 + gcol, &Als[cc << 9]);
            else
                gld16(W + (size_t)(n0 + row) * DMODEL + k0 + gcol, &Bls[cc << 9]);
        }
        __syncthreads();

#pragma unroll
        for (int kk = 0; kk < 2; kk++) {
            short8 af[MI], bfv[4];
            const int u = kk * 4 + lg;
#pragma unroll
            for (int i = 0; i < MI; i++) {
                const int r = wm * (BM / 2) + i * 16 + lr;
                af[i] = *(const short8*)&Als[r * 64 + ((u ^ (r & 7)) << 3)];
            }
#pragma unroll
            for (int j = 0; j < 4; j++) {
                const int r = wn * 64 + j * 16 + lr;
                bfv[j] = *(const short8*)&Bls[r * 64 + ((u ^ (r & 7)) << 3)];
            }
#pragma unroll
            for (int i = 0; i < MI; i++)
#pragma unroll
                for (int j = 0; j < 4; j++)
                    acc[i][j] = __builtin_amdgcn_mfma_f32_16x16x32_bf16(af[i], bfv[j], acc[i][j], 0, 0, 0);
        }
    }

#pragma unroll
    for (int i = 0; i < MI; i++) {
        const int rbase = m0 + wm * (BM / 2) + i * 16 + lg * 4;
#pragma unroll
        for (int j = 0; j < 4; j++) {
            const int cg = n0 + wn * 64 + j * 16 + lr;
            if constexpr (MODE == 1) {
                const float bb = bias0[cg];
#pragma unroll
                for (int p = 0; p < 4; p++)
                    Of[(size_t)(rbase + p) * DMODEL + cg] = acc[i][j][p] + bb;
            } else {
                const int sel = cg >> 10, cw = cg & 1023;
                const int h = cw >> 6, d = cw & 63;
                const float bb = (sel == 0 ? bias0 : sel == 1 ? bias1 : bias2)[cw];
                const int b = rbase >> 11, s = rbase & (SEQ - 1);
                if (sel == 2) {
                    uint2 pk;
                    pk.x = (uint)f2bf(acc[i][j][0] + bb) | ((uint)f2bf(acc[i][j][1] + bb) << 16);
                    pk.y = (uint)f2bf(acc[i][j][2] + bb) | ((uint)f2bf(acc[i][j][3] + bb) << 16);
                    *(uint2*)&Ov[((size_t)(b * NHEAD + h) * DKH + d) * SEQ + s] = pk;
                } else if (sel == 0) {
                    uint2 pk;
                    pk.x = (uint)f2bf((acc[i][j][0] + bb) * SCL) |
                           ((uint)f2bf((acc[i][j][1] + bb) * SCL) << 16);
                    pk.y = (uint)f2bf((acc[i][j][2] + bb) * SCL) |
                           ((uint)f2bf((acc[i][j][3] + bb) * SCL) << 16);
                    *(uint2*)&Oq[((size_t)(b * NHEAD + h) * DKH + d) * SEQ + s] = pk;
                } else {
#pragma unroll
                    for (int p = 0; p < 4; p++)
                        Ok[((size_t)(b * NHEAD + h) * SEQ + s + p) * DKH + d] = f2bf(acc[i][j][p] + bb);
                }
            }
        }
    }
}

// ---------------------------------------------------------------------------
// Flash attention, 32x32x16-MFMA structure (m214-style):
//  - swapped QK^T (S^T = K*Q^T): C col = lane&31 = q -> m/l/corr lane-local
//  - P stays IN REGISTERS: 16 cvt_pk + 8 permlane32_swap build PV B-frags
//    (lane needs j<4 from its <32 partner, j>=4 from its >=32 partner;
//    swapping w[m]<->w[m+2] yields the frag words directly)
//  - per wave-tile: 16 ds_read_b128 + 16 MFMA(32x32x16); no P LDS buffer
//  - 4 waves x 32 q = 128 q/block -> 512 blocks = 2 blocks/CU (r11 lesson)
//  - T1 XCD remap + T3 2-phase dbuf + T5 setprio + T13 defer-max
// Q input TRANSPOSED [B,H,64,S] (pre-scaled by SCL).
// ---------------------------------------------------------------------------
__global__ __launch_bounds__(256) void attn_kernel(
    const ushort* __restrict__ Qt, const ushort* __restrict__ K,
    const ushort* __restrict__ Vt, ushort* __restrict__ O) {
    constexpr int KT = 64, NT = SEQ / KT;
    __shared__ ushort Kls0[KT * 64], Kls1[KT * 64];   // [kpos][d], swizzled slots
    __shared__ ushort Vls0[KT * 64], Vls1[KT * 64];   // [d][kpos], swizzled slots

    const int tid = threadIdx.x;
    const int w = tid >> 6, l = tid & 63;
    const int q32 = l & 31, hl = l >> 5, l7 = l & 7;
    // T1 remap: same-head blocks share an XCD (512 blocks)
    const int l0 = blockIdx.x;
    const int bh = (l0 & 7) + ((l0 >> 7) << 3);
    const int q0 = ((l0 >> 3) & 15) * 128;
    const int qb = q0 + w * 32;                       // wave's 32-q base
    const ushort* Qh = Qt + (size_t)bh * DKH * SEQ;
    const ushort* Kh = K  + (size_t)bh * SEQ * DKH;
    const ushort* Vh = Vt + (size_t)bh * DKH * SEQ;

    // Q B-frags (QK^T): qf[c] elem j = Q^T[d = 16c + 8*hl + j][q = qb + q32]
    short8 qf[4];
#pragma unroll
    for (int c = 0; c < 4; c++)
#pragma unroll
        for (int j = 0; j < 8; j++)
            ((ushort*)&qf[c])[j] = Qh[(size_t)(16 * c + 8 * hl + j) * SEQ + qb + q32];

    // staging: wave w stages rows w*16..w*16+15 (two 8-row halves)
    const int sr8 = l >> 3;
    const int scol = ((l & 7) ^ (sr8 & 7)) * 8;       // pre-swizzled source col
    const ushort* Kg = Kh + (size_t)(w * 16 + sr8) * DKH + scol;
    const ushort* Vg = Vh + (size_t)(w * 16 + sr8) * SEQ + scol;

    floatx16 acc0 = {}, acc1 = {};
    float mrun = -3e38f, lrun = 0.f;

    auto stage = [&](int t, ushort* kd, ushort* vd) {
        gld16(Kg + (size_t)t * (KT * DKH),           kd + w * 1024);
        gld16(Kg + (size_t)t * (KT * DKH) + 8 * DKH, kd + w * 1024 + 512);
        gld16(Vg + (size_t)t * KT,                   vd + w * 1024);
        gld16(Vg + (size_t)t * KT + 8 * SEQ,         vd + w * 1024 + 512);
    };

    auto compute = [&](const ushort* kb, const ushort* vb) {
        // ---- QK^T: sa0 = S^T[k 0..31][q], sa1 = S^T[k 32..63][q]
        floatx16 sa0 = {}, sa1 = {};
        __builtin_amdgcn_s_setprio(1);
#pragma unroll
        for (int c = 0; c < 4; c++) {
            const int sl = (((2 * c + hl) ^ l7) << 3);
            const short8 kf0 = *(const short8*)&kb[q32 * 64 + sl];
            const short8 kf1 = *(const short8*)&kb[(32 + q32) * 64 + sl];
            sa0 = __builtin_amdgcn_mfma_f32_32x32x16_bf16(kf0, qf[c], sa0, 0, 0, 0);
            sa1 = __builtin_amdgcn_mfma_f32_32x32x16_bf16(kf1, qf[c], sa1, 0, 0, 0);
        }
        __builtin_amdgcn_s_setprio(0);

        // ---- in-lane softmax over the 32 held scores (+ partner via xor 32)
        float mx = fmaxf(sa0[0], sa0[1]);
#pragma unroll
        for (int i = 2; i < 16; i++) mx = fmaxf(mx, sa0[i]);
#pragma unroll
        for (int i = 0; i < 16; i++) mx = fmaxf(mx, sa1[i]);
        mx = fmaxf(mx, __shfl_xor(mx, 32));
        if (__any(mx - mrun > 10.0f)) {               // T13 defer-max
            const float mn = fmaxf(mrun, mx);
            const float corr = exp2f(mrun - mn);
            mrun = mn;
            lrun *= corr;
#pragma unroll
            for (int i = 0; i < 16; i++) { acc0[i] *= corr; acc1[i] *= corr; }
        }
        float ps = 0.f;
#pragma unroll
        for (int i = 0; i < 16; i++) { sa0[i] = exp2f(sa0[i] - mrun); ps += sa0[i]; }
#pragma unroll
        for (int i = 0; i < 16; i++) { sa1[i] = exp2f(sa1[i] - mrun); ps += sa1[i]; }
        ps += __shfl_xor(ps, 32);
        lrun += ps;

        // ---- P -> bf16 in-register + permlane32_swap lane-exchange
        short8 pf[4];
#pragma unroll
        for (int t = 0; t < 2; t++) {
            uint wd[8];
#pragma unroll
            for (int m = 0; m < 8; m++) {
                const float a = t ? sa1[2 * m] : sa0[2 * m];
                const float b = t ? sa1[2 * m + 1] : sa0[2 * m + 1];
                asm("v_cvt_pk_bf16_f32 %0, %1, %2" : "=v"(wd[m]) : "v"(a), "v"(b));
            }
            asm volatile("v_permlane32_swap_b32 %0, %1" : "+v"(wd[0]), "+v"(wd[2]));
            asm volatile("v_permlane32_swap_b32 %0, %1" : "+v"(wd[1]), "+v"(wd[3]));
            asm volatile("v_permlane32_swap_b32 %0, %1" : "+v"(wd[4]), "+v"(wd[6]));
            asm volatile("v_permlane32_swap_b32 %0, %1" : "+v"(wd[5]), "+v"(wd[7]));
            uintx4 f0 = {wd[0], wd[1], wd[2], wd[3]};
            uintx4 f1 = {wd[4], wd[5], wd[6], wd[7]};
            pf[2 * t]     = __builtin_bit_cast(short8, f0);
            pf[2 * t + 1] = __builtin_bit_cast(short8, f1);
        }

        // ---- PV: O^T[d][q] += V^T[d][k] * P^T[k][q]
        __builtin_amdgcn_s_setprio(1);
#pragma unroll
        for (int c = 0; c < 4; c++) {
            const int sl = (((2 * c + hl) ^ l7) << 3);
            const short8 vf0 = *(const short8*)&vb[q32 * 64 + sl];
            const short8 vf1 = *(const short8*)&vb[(32 + q32) * 64 + sl];
            acc0 = __builtin_amdgcn_mfma_f32_32x32x16_bf16(vf0, pf[c], acc0, 0, 0, 0);
            acc1 = __builtin_amdgcn_mfma_f32_32x32x16_bf16(vf1, pf[c], acc1, 0, 0, 0);
        }
        __builtin_amdgcn_s_setprio(0);
    };

    // T3-minimum pipeline: prefetch next tile before computing current;
    // one barrier per tile (drains vmcnt -> prefetched tile ready).
    stage(0, Kls0, Vls0);
    __syncthreads();
#pragma unroll 1
    for (int it = 0; it < NT / 2 - 1; it++) {
        stage(2 * it + 1, Kls1, Vls1);
        compute(Kls0, Vls0);
        __syncthreads();
        stage(2 * it + 2, Kls0, Vls0);
        compute(Kls1, Vls1);
        __syncthreads();
    }
    stage(NT - 1, Kls1, Vls1);
    compute(Kls0, Vls0);
    __syncthreads();
    compute(Kls1, Vls1);

    // ---- epilogue: lane-local divide; d packed 4-wide (8B stores)
    const int b = bh >> 4, h = bh & (NHEAD - 1);
    const float inv = 1.0f / lrun;
    ushort* Ob = O + (size_t)(b * SEQ + qb + q32) * DMODEL + h * DKH;
#pragma unroll
    for (int g = 0; g < 2; g++) {
#pragma unroll
        for (int u = 0; u < 4; u++) {
            const float v0 = (g ? acc1[4 * u]     : acc0[4 * u])     * inv;
            const float v1 = (g ? acc1[4 * u + 1] : acc0[4 * u + 1]) * inv;
            const float v2 = (g ? acc1[4 * u + 2] : acc0[4 * u + 2]) * inv;
            const float v3 = (g ? acc1[4 * u + 3] : acc0[4 * u + 3]) * inv;
            uint2 pk;
            pk.x = (uint)f2bf(v0) | ((uint)f2bf(v1) << 16);
            pk.y = (uint)f2bf(v2) | ((uint)f2bf(v3) << 16);
            *(uint2*)&Ob[g * 32 + u * 8 + hl * 4] = pk;
        }
    }
}

// ---------------------------------------------------------------------------
extern "C" void kernel_launch(void* const* d_in, const int* in_sizes, int n_in,
                              void* d_out, int out_size, void* d_ws, size_t ws_size,
                              hipStream_t stream) {
    const float* x  = (const float*)d_in[0];
    const float* Wq = (const float*)d_in[1];
    const float* bq = (const float*)d_in[2];
    const float* Wk = (const float*)d_in[3];
    const float* bk = (const float*)d_in[4];
    const float* Wv = (const float*)d_in[5];
    const float* bv = (const float*)d_in[6];
    const float* Wo = (const float*)d_in[7];
    const float* bo = (const float*)d_in[8];

    ushort* base = (ushort*)d_ws;
    ushort* xb  = base;                                  // 4M bf16
    ushort* wc  = xb  + (size_t)4 * 1024 * 1024;         // 3M  (Wq|Wk|Wv)
    ushort* wob = wc  + (size_t)3 * 1024 * 1024;         // 1M
    ushort* qws = wob + (size_t)1 * 1024 * 1024;         // 4M  Q^T [B,H,64,S] (pre-scaled)
    ushort* kws = qws + (size_t)4 * 1024 * 1024;         // 4M  K [B,H,S,64]
    ushort* vws = kws + (size_t)4 * 1024 * 1024;         // 4M  V^T [B,H,64,S]
    ushort* aws = vws + (size_t)4 * 1024 * 1024;         // 4M  attn out bf16

    hipLaunchKernelGGL(cvt_kernel, dim3(8192), dim3(256), 0, stream,
                       x, Wq, Wk, Wv, Wo, xb, wc, wob);

    hipLaunchKernelGGL((gemm_bf16<2, 0>), dim3(MTOT / 128, 3072 / 128), dim3(256), 0, stream,
                       xb, wc, bq, bk, bv, qws, kws, vws, (float*)nullptr);

    hipLaunchKernelGGL(attn_kernel, dim3(512), dim3(256), 0, stream,
                       qws, kws, vws, aws);

    hipLaunchKernelGGL((gemm_bf16<1, 1>), dim3(MTOT / 64, DMODEL / 128), dim3(256), 0, stream,
                       aws, wob, bo, (const float*)nullptr, (const float*)nullptr,
                       (ushort*)nullptr, (ushort*)nullptr, (ushort*)nullptr, (float*)d_out);
}

// Round 13
// 133.157 us; speedup vs baseline: 1.0593x; 1.0219x over previous
//
#include <hip/hip_runtime.h>

constexpr int DMODEL = 1024;
constexpr int NHEAD  = 16;
constexpr int DKH    = 64;
constexpr int BATCH  = 2;
constexpr int SEQ    = 2048;
constexpr int MTOT   = BATCH * SEQ;   // 4096
constexpr float SCL  = 0.18033688011112042f;   // (1/sqrt(64)) * log2(e)

typedef __attribute__((ext_vector_type(8)))  short short8;
typedef __attribute__((ext_vector_type(4)))  float floatx4;
typedef __attribute__((ext_vector_type(16))) float floatx16;
typedef __attribute__((ext_vector_type(4)))  uint  uintx4;

// fp32 -> bf16 round-to-nearest-even
__device__ __forceinline__ ushort f2bf(float f) {
    unsigned u = __builtin_bit_cast(unsigned, f);
    u = (u + 0x7fffu + ((u >> 16) & 1u)) >> 16;
    return (ushort)u;
}

__device__ __forceinline__ float max3f(float a, float b, float c) {
    float r;
    asm("v_max3_f32 %0, %1, %2, %3" : "=v"(r) : "v"(a), "v"(b), "v"(c));
    return r;
}

// async 16B global->LDS (HW writes lds_base + lane*16)
__device__ __forceinline__ void gld16(const ushort* g, ushort* l) {
    __builtin_amdgcn_global_load_lds(
        (const __attribute__((address_space(1))) void*)g,
        (__attribute__((address_space(3))) void*)l, 16, 0, 0);
}

// ---------------------------------------------------------------------------
// Convert pass: x -> xb bf16; Wq/Wk/Wv -> wc bf16 [3072,1024]; Wo -> wob bf16.
// ---------------------------------------------------------------------------
__global__ __launch_bounds__(256) void cvt_kernel(
    const float* __restrict__ x,  const float* __restrict__ wq,
    const float* __restrict__ wk, const float* __restrict__ wv,
    const float* __restrict__ wo,
    ushort* __restrict__ xb, ushort* __restrict__ wc, ushort* __restrict__ wob) {
    const int id = blockIdx.x * 256 + threadIdx.x;        // 0 .. 2M-1
    const float* src;
    ushort* dst;
    if (id < (1 << 20)) {
        src = x + (size_t)id * 4;
        dst = xb + (size_t)id * 4;
    } else {
        const int t = id - (1 << 20);
        const int seg = t >> 18;                           // 0..3
        const size_t off = (size_t)(t & 0x3ffff) * 4;
        src = (seg == 0 ? wq : seg == 1 ? wk : seg == 2 ? wv : wo) + off;
        dst = (seg < 3) ? (wc + ((size_t)seg << 20) + off) : (wob + off);
    }
    const float4 v = *(const float4*)src;
    uint2 o;
    o.x = (uint)f2bf(v.x) | ((uint)f2bf(v.y) << 16);
    o.y = (uint)f2bf(v.z) | ((uint)f2bf(v.w) << 16);
    *(uint2*)dst = o;
}

// ---------------------------------------------------------------------------
// bf16 GEMM  Y = A @ W^T + bias (NT).  BK=64, global_load_lds(16B), XOR
// swizzle via pre-swizzled global source.  2D grid (r9 form).
// MODE 0: fused QKV epilogue -> Q^T [B,H,64,S] (scaled), K [B,H,S,64],
//         V^T [B,H,64,S].   MODE 1: fp32 [M,1024] output.
// ---------------------------------------------------------------------------
template <int BMT, int MODE>
__global__ __launch_bounds__(256) void gemm_bf16(
    const ushort* __restrict__ A, const ushort* __restrict__ W,
    const float* __restrict__ bias0, const float* __restrict__ bias1,
    const float* __restrict__ bias2,
    ushort* __restrict__ Oq, ushort* __restrict__ Ok, ushort* __restrict__ Ov,
    float* __restrict__ Of) {
    constexpr int BM = 64 * BMT, BN = 128, BK = 64;
    constexpr int MI = 2 * BMT;
    constexpr int CA = BM / 8, CT = CA + BN / 8, NISS = CT / 4;
    __shared__ ushort Als[BM * BK];
    __shared__ ushort Bls[BN * BK];

    const int tid = threadIdx.x;
    const int w = tid >> 6, l = tid & 63;
    const int lr = l & 15, lg = l >> 4;
    const int wm = w >> 1, wn = w & 1;
    const int m0 = blockIdx.x * BM, n0 = blockIdx.y * BN;

    floatx4 acc[MI][4] = {};

    for (int k0 = 0; k0 < DMODEL; k0 += BK) {
        __syncthreads();
#pragma unroll
        for (int i = 0; i < NISS; i++) {
            const int c = w * NISS + i;
            const int cc = (c < CA) ? c : c - CA;
            const int row = (cc << 3) + (l >> 3);
            const int gcol = (((l & 7) ^ (row & 7)) << 3);
            if (c < CA)
                gld16(A + (size_t)(m0 + row) * DMODEL + k0 + gcol, &Als[cc << 9]);
            else
                gld16(W + (size_t)(n0 + row) * DMODEL + k0 + gcol, &Bls[cc << 9]);
        }
        __syncthreads();

#pragma unroll
        for (int kk = 0; kk < 2; kk++) {
            short8 af[MI], bfv[4];
            const int u = kk * 4 + lg;
#pragma unroll
            for (int i = 0; i < MI; i++) {
                const int r = wm * (BM / 2) + i * 16 + lr;
                af[i] = *(const short8*)&Als[r * 64 + ((u ^ (r & 7)) << 3)];
            }
#pragma unroll
            for (int j = 0; j < 4; j++) {
                const int r = wn * 64 + j * 16 + lr;
                bfv[j] = *(const short8*)&Bls[r * 64 + ((u ^ (r & 7)) << 3)];
            }
#pragma unroll
            for (int i = 0; i < MI; i++)
#pragma unroll
                for (int j = 0; j < 4; j++)
                    acc[i][j] = __builtin_amdgcn_mfma_f32_16x16x32_bf16(af[i], bfv[j], acc[i][j], 0, 0, 0);
        }
    }

#pragma unroll
    for (int i = 0; i < MI; i++) {
        const int rbase = m0 + wm * (BM / 2) + i * 16 + lg * 4;
#pragma unroll
        for (int j = 0; j < 4; j++) {
            const int cg = n0 + wn * 64 + j * 16 + lr;
            if constexpr (MODE == 1) {
                const float bb = bias0[cg];
#pragma unroll
                for (int p = 0; p < 4; p++)
                    Of[(size_t)(rbase + p) * DMODEL + cg] = acc[i][j][p] + bb;
            } else {
                const int sel = cg >> 10, cw = cg & 1023;
                const int h = cw >> 6, d = cw & 63;
                const float bb = (sel == 0 ? bias0 : sel == 1 ? bias1 : bias2)[cw];
                const int b = rbase >> 11, s = rbase & (SEQ - 1);
                if (sel == 2) {
                    uint2 pk;
                    pk.x = (uint)f2bf(acc[i][j][0] + bb) | ((uint)f2bf(acc[i][j][1] + bb) << 16);
                    pk.y = (uint)f2bf(acc[i][j][2] + bb) | ((uint)f2bf(acc[i][j][3] + bb) << 16);
                    *(uint2*)&Ov[((size_t)(b * NHEAD + h) * DKH + d) * SEQ + s] = pk;
                } else if (sel == 0) {
                    uint2 pk;
                    pk.x = (uint)f2bf((acc[i][j][0] + bb) * SCL) |
                           ((uint)f2bf((acc[i][j][1] + bb) * SCL) << 16);
                    pk.y = (uint)f2bf((acc[i][j][2] + bb) * SCL) |
                           ((uint)f2bf((acc[i][j][3] + bb) * SCL) << 16);
                    *(uint2*)&Oq[((size_t)(b * NHEAD + h) * DKH + d) * SEQ + s] = pk;
                } else {
#pragma unroll
                    for (int p = 0; p < 4; p++)
                        Ok[((size_t)(b * NHEAD + h) * SEQ + s + p) * DKH + d] = f2bf(acc[i][j][p] + bb);
                }
            }
        }
    }
}

// ---------------------------------------------------------------------------
// Flash attention, 32x32x16-MFMA structure:
//  - swapped QK^T: C col = lane&31 = q -> m/corr lane-local
//  - P in registers: 16 cvt_pk + 8 permlane32_swap -> PV B-frags (r12-proven)
//  - l-sum via ones-MFMA over P-frags (covers all 64 k, no shfl, no ps adds)
//  - v_max3_f32 tree for the row max
//  - 4 waves x 32 q = 128 q/block -> 512 blocks = 2 blocks/CU
//  - T1 XCD remap + T3 2-phase dbuf + T5 setprio + T13 defer-max
// Q input TRANSPOSED [B,H,64,S] (pre-scaled by SCL).
// ---------------------------------------------------------------------------
__global__ __launch_bounds__(256) void attn_kernel(
    const ushort* __restrict__ Qt, const ushort* __restrict__ K,
    const ushort* __restrict__ Vt, ushort* __restrict__ O) {
    constexpr int KT = 64, NT = SEQ / KT;
    __shared__ ushort Kls0[KT * 64], Kls1[KT * 64];   // [kpos][d], swizzled slots
    __shared__ ushort Vls0[KT * 64], Vls1[KT * 64];   // [d][kpos], swizzled slots

    const int tid = threadIdx.x;
    const int w = tid >> 6, l = tid & 63;
    const int q32 = l & 31, hl = l >> 5, l7 = l & 7;
    // T1 remap: same-head blocks share an XCD (512 blocks)
    const int l0 = blockIdx.x;
    const int bh = (l0 & 7) + ((l0 >> 7) << 3);
    const int q0 = ((l0 >> 3) & 15) * 128;
    const int qb = q0 + w * 32;                       // wave's 32-q base
    const ushort* Qh = Qt + (size_t)bh * DKH * SEQ;
    const ushort* Kh = K  + (size_t)bh * SEQ * DKH;
    const ushort* Vh = Vt + (size_t)bh * DKH * SEQ;

    // Q B-frags (QK^T): qf[c] elem j = Q^T[d = 16c + 8*hl + j][q = qb + q32]
    short8 qf[4];
#pragma unroll
    for (int c = 0; c < 4; c++)
#pragma unroll
        for (int j = 0; j < 8; j++)
            ((ushort*)&qf[c])[j] = Qh[(size_t)(16 * c + 8 * hl + j) * SEQ + qb + q32];

    // bf16 ones vector for the l-sum MFMA
    short8 ones;
#pragma unroll
    for (int j = 0; j < 8; j++) ones[j] = (short)0x3F80;

    // staging: wave w stages rows w*16..w*16+15 (two 8-row halves)
    const int sr8 = l >> 3;
    const int scol = ((l & 7) ^ (sr8 & 7)) * 8;       // pre-swizzled source col
    const ushort* Kg = Kh + (size_t)(w * 16 + sr8) * DKH + scol;
    const ushort* Vg = Vh + (size_t)(w * 16 + sr8) * SEQ + scol;

    floatx16 acc0 = {}, acc1 = {}, accl = {};
    float mrun = -3e38f;

    auto stage = [&](int t, ushort* kd, ushort* vd) {
        gld16(Kg + (size_t)t * (KT * DKH),           kd + w * 1024);
        gld16(Kg + (size_t)t * (KT * DKH) + 8 * DKH, kd + w * 1024 + 512);
        gld16(Vg + (size_t)t * KT,                   vd + w * 1024);
        gld16(Vg + (size_t)t * KT + 8 * SEQ,         vd + w * 1024 + 512);
    };

    auto compute = [&](const ushort* kb, const ushort* vb) {
        // ---- QK^T: sa0 = S^T[k 0..31][q], sa1 = S^T[k 32..63][q]
        floatx16 sa0 = {}, sa1 = {};
        __builtin_amdgcn_s_setprio(1);
#pragma unroll
        for (int c = 0; c < 4; c++) {
            const int sl = (((2 * c + hl) ^ l7) << 3);
            const short8 kf0 = *(const short8*)&kb[q32 * 64 + sl];
            const short8 kf1 = *(const short8*)&kb[(32 + q32) * 64 + sl];
            sa0 = __builtin_amdgcn_mfma_f32_32x32x16_bf16(kf0, qf[c], sa0, 0, 0, 0);
            sa1 = __builtin_amdgcn_mfma_f32_32x32x16_bf16(kf1, qf[c], sa1, 0, 0, 0);
        }
        __builtin_amdgcn_s_setprio(0);

        // ---- row max via v_max3 tree (31 ops -> ~16)
        float m0a = max3f(sa0[0],  sa0[1],  sa0[2]);
        float m1a = max3f(sa0[3],  sa0[4],  sa0[5]);
        float m2a = max3f(sa0[6],  sa0[7],  sa0[8]);
        float m3a = max3f(sa0[9],  sa0[10], sa0[11]);
        float m4a = max3f(sa0[12], sa0[13], sa0[14]);
        float m0b = max3f(sa1[0],  sa1[1],  sa1[2]);
        float m1b = max3f(sa1[3],  sa1[4],  sa1[5]);
        float m2b = max3f(sa1[6],  sa1[7],  sa1[8]);
        float m3b = max3f(sa1[9],  sa1[10], sa1[11]);
        float m4b = max3f(sa1[12], sa1[13], sa1[14]);
        float mx = max3f(max3f(m0a, m1a, m2a), max3f(m3a, m4a, sa0[15]),
                         max3f(max3f(m0b, m1b, m2b), max3f(m3b, m4b, sa1[15]),
                               -3e38f));
        mx = fmaxf(mx, __shfl_xor(mx, 32));
        if (__any(mx - mrun > 10.0f)) {               // T13 defer-max
            const float mn = fmaxf(mrun, mx);
            const float corr = exp2f(mrun - mn);
            mrun = mn;
            accl[0] *= corr;
#pragma unroll
            for (int i = 0; i < 16; i++) { acc0[i] *= corr; acc1[i] *= corr; }
        }
#pragma unroll
        for (int i = 0; i < 16; i++) sa0[i] = exp2f(sa0[i] - mrun);
#pragma unroll
        for (int i = 0; i < 16; i++) sa1[i] = exp2f(sa1[i] - mrun);

        // ---- P -> bf16 in-register + permlane32_swap lane-exchange
        short8 pf[4];
#pragma unroll
        for (int t = 0; t < 2; t++) {
            uint wd[8];
#pragma unroll
            for (int m = 0; m < 8; m++) {
                const float a = t ? sa1[2 * m] : sa0[2 * m];
                const float b = t ? sa1[2 * m + 1] : sa0[2 * m + 1];
                asm("v_cvt_pk_bf16_f32 %0, %1, %2" : "=v"(wd[m]) : "v"(a), "v"(b));
            }
            asm volatile("v_permlane32_swap_b32 %0, %1" : "+v"(wd[0]), "+v"(wd[2]));
            asm volatile("v_permlane32_swap_b32 %0, %1" : "+v"(wd[1]), "+v"(wd[3]));
            asm volatile("v_permlane32_swap_b32 %0, %1" : "+v"(wd[4]), "+v"(wd[6]));
            asm volatile("v_permlane32_swap_b32 %0, %1" : "+v"(wd[5]), "+v"(wd[7]));
            uintx4 f0 = {wd[0], wd[1], wd[2], wd[3]};
            uintx4 f1 = {wd[4], wd[5], wd[6], wd[7]};
            pf[2 * t]     = __builtin_bit_cast(short8, f0);
            pf[2 * t + 1] = __builtin_bit_cast(short8, f1);
        }

        // ---- PV + l-sum: O^T[d][q] += V^T[d][k] P^T[k][q];  l[q] += 1^T P^T
        __builtin_amdgcn_s_setprio(1);
#pragma unroll
        for (int c = 0; c < 4; c++) {
            const int sl = (((2 * c + hl) ^ l7) << 3);
            const short8 vf0 = *(const short8*)&vb[q32 * 64 + sl];
            const short8 vf1 = *(const short8*)&vb[(32 + q32) * 64 + sl];
            acc0 = __builtin_amdgcn_mfma_f32_32x32x16_bf16(vf0, pf[c], acc0, 0, 0, 0);
            acc1 = __builtin_amdgcn_mfma_f32_32x32x16_bf16(vf1, pf[c], acc1, 0, 0, 0);
            accl = __builtin_amdgcn_mfma_f32_32x32x16_bf16(ones, pf[c], accl, 0, 0, 0);
        }
        __builtin_amdgcn_s_setprio(0);
    };

    // T3-minimum pipeline: prefetch next tile before computing current;
    // one barrier per tile (drains vmcnt -> prefetched tile ready).
    stage(0, Kls0, Vls0);
    __syncthreads();
#pragma unroll 1
    for (int it = 0; it < NT / 2 - 1; it++) {
        stage(2 * it + 1, Kls1, Vls1);
        compute(Kls0, Vls0);
        __syncthreads();
        stage(2 * it + 2, Kls0, Vls0);
        compute(Kls1, Vls1);
        __syncthreads();
    }
    stage(NT - 1, Kls1, Vls1);
    compute(Kls0, Vls0);
    __syncthreads();
    compute(Kls1, Vls1);

    // ---- epilogue: lane-local divide; d packed 4-wide (8B stores)
    const int b = bh >> 4, h = bh & (NHEAD - 1);
    const float inv = 1.0f / accl[0];
    ushort* Ob = O + (size_t)(b * SEQ + qb + q32) * DMODEL + h * DKH;
#pragma unroll
    for (int g = 0; g < 2; g++) {
#pragma unroll
        for (int u = 0; u < 4; u++) {
            const float v0 = (g ? acc1[4 * u]     : acc0[4 * u])     * inv;
            const float v1 = (g ? acc1[4 * u + 1] : acc0[4 * u + 1]) * inv;
            const float v2 = (g ? acc1[4 * u + 2] : acc0[4 * u + 2]) * inv;
            const float v3 = (g ? acc1[4 * u + 3] : acc0[4 * u + 3]) * inv;
            uint2 pk;
            pk.x = (uint)f2bf(v0) | ((uint)f2bf(v1) << 16);
            pk.y = (uint)f2bf(v2) | ((uint)f2bf(v3) << 16);
            *(uint2*)&Ob[g * 32 + u * 8 + hl * 4] = pk;
        }
    }
}

// ---------------------------------------------------------------------------
extern "C" void kernel_launch(void* const* d_in, const int* in_sizes, int n_in,
                              void* d_out, int out_size, void* d_ws, size_t ws_size,
                              hipStream_t stream) {
    const float* x  = (const float*)d_in[0];
    const float* Wq = (const float*)d_in[1];
    const float* bq = (const float*)d_in[2];
    const float* Wk = (const float*)d_in[3];
    const float* bk = (const float*)d_in[4];
    const float* Wv = (const float*)d_in[5];
    const float* bv = (const float*)d_in[6];
    const float* Wo = (const float*)d_in[7];
    const float* bo = (const float*)d_in[8];

    ushort* base = (ushort*)d_ws;
    ushort* xb  = base;                                  // 4M bf16
    ushort* wc  = xb  + (size_t)4 * 1024 * 1024;         // 3M  (Wq|Wk|Wv)
    ushort* wob = wc  + (size_t)3 * 1024 * 1024;         // 1M
    ushort* qws = wob + (size_t)1 * 1024 * 1024;         // 4M  Q^T [B,H,64,S] (pre-scaled)
    ushort* kws = qws + (size_t)4 * 1024 * 1024;         // 4M  K [B,H,S,64]
    ushort* vws = kws + (size_t)4 * 1024 * 1024;         // 4M  V^T [B,H,64,S]
    ushort* aws = vws + (size_t)4 * 1024 * 1024;         // 4M  attn out bf16

    hipLaunchKernelGGL(cvt_kernel, dim3(8192), dim3(256), 0, stream,
                       x, Wq, Wk, Wv, Wo, xb, wc, wob);

    hipLaunchKernelGGL((gemm_bf16<2, 0>), dim3(MTOT / 128, 3072 / 128), dim3(256), 0, stream,
                       xb, wc, bq, bk, bv, qws, kws, vws, (float*)nullptr);

    hipLaunchKernelGGL(attn_kernel, dim3(512), dim3(256), 0, stream,
                       qws, kws, vws, aws);

    hipLaunchKernelGGL((gemm_bf16<1, 1>), dim3(MTOT / 64, DMODEL / 128), dim3(256), 0, stream,
                       aws, wob, bo, (const float*)nullptr, (const float*)nullptr,
                       (ushort*)nullptr, (ushort*)nullptr, (ushort*)nullptr, (float*)d_out);
}